// Round 2
// baseline (247.926 us; speedup 1.0000x reference)
//
#include <hip/hip_runtime.h>
#include <hip/hip_bf16.h>

using bf16 = __hip_bfloat16;
using s16x8 = __attribute__((ext_vector_type(8))) short;
using f32x4 = __attribute__((ext_vector_type(4))) float;
typedef unsigned short u16;
typedef unsigned int u32;

#define DEVINL __device__ __forceinline__

DEVINL u16 f2bf(float f) {
  u32 u = __float_as_uint(f);
  u32 r = (u + 0x7fffu + ((u >> 16) & 1u)) >> 16;
  return (u16)r;
}

DEVINL void gload_lds16(const void* g, void* l) {
  __builtin_amdgcn_global_load_lds(
      (__attribute__((address_space(1))) void*)(void*)(g),
      (__attribute__((address_space(3))) void*)(l), 16, 0, 0);
}

// ---------------- cast x: fp32 -> bf16, 8 elems/thread ----------------
__global__ __launch_bounds__(256) void cast_f32_bf16(
    const float* __restrict__ in, bf16* __restrict__ out, int n) {
  int i = (blockIdx.x * 256 + threadIdx.x) * 8;
  float4 a = *(const float4*)(in + i);
  float4 b = *(const float4*)(in + i + 4);
  u16 tmp[8] = {f2bf(a.x), f2bf(a.y), f2bf(a.z), f2bf(a.w),
                f2bf(b.x), f2bf(b.y), f2bf(b.z), f2bf(b.w)};
  *(uint4*)(out + i) = *(const uint4*)tmp;
}

// -------- transpose+cast: W [K][N] fp32 -> Wt [N][K] bf16, 64x64 tiles --------
__global__ __launch_bounds__(256) void transpose_cast(
    const float* __restrict__ W, bf16* __restrict__ Wt, int K, int N) {
  __shared__ float tile[64][65];
  int n0 = blockIdx.x * 64, k0 = blockIdx.y * 64;
  int t = threadIdx.x;
#pragma unroll
  for (int i = 0; i < 16; ++i) {
    int idx = i * 256 + t;
    int r = idx >> 6, c = idx & 63;
    tile[r][c] = W[(size_t)(k0 + r) * N + n0 + c];
  }
  __syncthreads();
#pragma unroll
  for (int i = 0; i < 16; ++i) {
    int idx = i * 256 + t;
    int r = idx >> 6, c = idx & 63;
    Wt[(size_t)(n0 + r) * K + k0 + c] = __float2bfloat16(tile[c][r]);
  }
}

// ---------------- GEMM: A[M,K] bf16 x Bt[N,K] bf16 -> C + bias ----------------
// MODE 0: write bf16 into q/k/v split buffers (col>>10 selects). MODE 1: fp32 out.
template <int MODE>
__global__ __launch_bounds__(256) void gemm_bt(
    const bf16* __restrict__ A, const bf16* __restrict__ Bt,
    const float* __restrict__ bias,
    bf16* __restrict__ q, bf16* __restrict__ k, bf16* __restrict__ v,
    float* __restrict__ outf, int M, int N, int K) {
  __shared__ bf16 As[128 * 64];
  __shared__ bf16 Bs[128 * 64];
  const int tid = threadIdx.x;
  const int w = tid >> 6, lane = tid & 63;
  const int lr = lane >> 4, lc = lane & 15;
  const int wr = w >> 1, wc = w & 1;
  const int m0 = blockIdx.x * 128, n0 = blockIdx.y * 128;

  f32x4 acc[4][4] = {};

  const int srow = lane >> 3;
  const int scolb = ((lane & 7) * 16) ^ (srow << 4);  // pre-swizzled source col (bytes)
  const char* Abase = (const char*)(A + (size_t)m0 * K);
  const char* Bbase = (const char*)(Bt + (size_t)n0 * K);
  const int Krow = K * 2;

  for (int kt = 0; kt < K; kt += 64) {
    __syncthreads();
#pragma unroll
    for (int c = 0; c < 4; ++c) {
      int row = w * 32 + c * 8 + srow;
      gload_lds16(Abase + (size_t)row * Krow + kt * 2 + scolb,
                  (char*)As + w * 4096 + c * 1024 + lane * 16);
    }
#pragma unroll
    for (int c = 0; c < 4; ++c) {
      int row = w * 32 + c * 8 + srow;
      gload_lds16(Bbase + (size_t)row * Krow + kt * 2 + scolb,
                  (char*)Bs + w * 4096 + c * 1024 + lane * 16);
    }
    __syncthreads();
#pragma unroll
    for (int ks = 0; ks < 2; ++ks) {
      s16x8 af[4], bfr[4];
#pragma unroll
      for (int mi = 0; mi < 4; ++mi) {
        int row = wr * 64 + mi * 16 + lc;
        int colb = (ks * 64 + lr * 16) ^ ((row & 7) << 4);
        af[mi] = *(const s16x8*)((const char*)As + row * 128 + colb);
      }
#pragma unroll
      for (int ni = 0; ni < 4; ++ni) {
        int row = wc * 64 + ni * 16 + lc;
        int colb = (ks * 64 + lr * 16) ^ ((row & 7) << 4);
        bfr[ni] = *(const s16x8*)((const char*)Bs + row * 128 + colb);
      }
#pragma unroll
      for (int mi = 0; mi < 4; ++mi)
#pragma unroll
        for (int ni = 0; ni < 4; ++ni)
          acc[mi][ni] = __builtin_amdgcn_mfma_f32_16x16x32_bf16(
              af[mi], bfr[ni], acc[mi][ni], 0, 0, 0);
    }
  }

#pragma unroll
  for (int mi = 0; mi < 4; ++mi) {
#pragma unroll
    for (int ni = 0; ni < 4; ++ni) {
      int col = n0 + wc * 64 + ni * 16 + lc;
      float bb = bias[col];
      int rowb = m0 + wr * 64 + mi * 16 + lr * 4;
#pragma unroll
      for (int r = 0; r < 4; ++r) {
        float val = acc[mi][ni][r] + bb;
        int row = rowb + r;
        if (MODE == 0) {
          bf16* o = (col < 1024) ? q : ((col < 2048) ? k : v);
          int cc = col & 1023;
          o[(size_t)row * 1024 + cc] = __float2bfloat16(val);
        } else {
          outf[(size_t)row * N + col] = val;
        }
      }
    }
  }
}

// ---------------- causal flash attention on per-head [2048,64] ----------------
__global__ __launch_bounds__(256) void attn_kernel(
    const bf16* __restrict__ qb, const bf16* __restrict__ kb,
    const bf16* __restrict__ vb, bf16* __restrict__ ob) {
  __shared__ bf16 Ks[64 * 64];   // [key][d], XOR-swizzled
  __shared__ bf16 Vt[64 * 64];   // [d][key], XOR-swizzled
  __shared__ bf16 Ps[128 * 64];  // [qlocal][key], XOR-swizzled

  const int idx = blockIdx.x;
  const int qt = 15 - (idx >> 5);  // long blocks first
  const int bh = idx & 31;
  const int b = bh >> 4, h = bh & 15;
  const size_t hb = ((size_t)(b * 2048 + h * 128)) * 1024;
  const bf16* qh = qb + hb;
  const bf16* kh = kb + hb;
  const bf16* vh = vb + hb;

  const int tid = threadIdx.x;
  const int w = tid >> 6, lane = tid & 63;
  const int lr = lane >> 4, lc = lane & 15;

  // Q fragments in registers: rows w*32 + mi*16 + lc, d = ks*32 + lr*8 + j
  s16x8 qf[2][2];
#pragma unroll
  for (int mi = 0; mi < 2; ++mi)
#pragma unroll
    for (int ks = 0; ks < 2; ++ks)
      qf[mi][ks] = *(const s16x8*)(qh + (size_t)(qt * 128 + w * 32 + mi * 16 + lc) * 64 +
                                   ks * 32 + lr * 8);

  f32x4 o_acc[2][4] = {};
  float m_run[2][4], l_run[2][4];
#pragma unroll
  for (int mi = 0; mi < 2; ++mi)
#pragma unroll
    for (int r = 0; r < 4; ++r) { m_run[mi][r] = -INFINITY; l_run[mi][r] = 0.f; }

  const int srow = lane >> 3;
  const int scolb = ((lane & 7) * 16) ^ (srow << 4);

  const int nt = (qt + 1) * 2;
  for (int t = 0; t < nt; ++t) {
    __syncthreads();
    // stage K tile (64x64) via global_load_lds, source pre-swizzled
#pragma unroll
    for (int c = 0; c < 2; ++c) {
      int row = w * 16 + c * 8 + srow;
      gload_lds16((const char*)(kh + (size_t)(t * 64 + row) * 64) + scolb,
                  (char*)Ks + w * 2048 + c * 1024 + lane * 16);
    }
    // stage V transposed: lane reads a 16B chunk of its own key-row, scatters d-major
#pragma unroll
    for (int c = 0; c < 2; ++c) {
      int key = lane;
      int d0 = (c * 4 + w) * 8;
      uint4 val = *(const uint4*)(vh + (size_t)(t * 64 + key) * 64 + d0);
      const u16* e = (const u16*)&val;
#pragma unroll
      for (int j = 0; j < 8; ++j) {
        int d = d0 + j;
        *(u16*)((char*)Vt + d * 128 + ((key * 2) ^ ((j & 7) << 4))) = e[j];
      }
    }
    __syncthreads();

    // S = Q K^T (wave owns 32 q rows x 64 keys)
    f32x4 s[2][4] = {};
#pragma unroll
    for (int ks = 0; ks < 2; ++ks) {
      s16x8 kf[4];
#pragma unroll
      for (int nj = 0; nj < 4; ++nj) {
        int row = nj * 16 + lc;
        int colb = (ks * 64 + lr * 16) ^ ((row & 7) << 4);
        kf[nj] = *(const s16x8*)((const char*)Ks + row * 128 + colb);
      }
#pragma unroll
      for (int mi = 0; mi < 2; ++mi)
#pragma unroll
        for (int nj = 0; nj < 4; ++nj)
          s[mi][nj] = __builtin_amdgcn_mfma_f32_16x16x32_bf16(
              qf[mi][ks], kf[nj], s[mi][nj], 0, 0, 0);
    }

    // online softmax; write P (bf16) into swizzled LDS
#pragma unroll
    for (int mi = 0; mi < 2; ++mi) {
#pragma unroll
      for (int r = 0; r < 4; ++r) {
        const int qlocal = w * 32 + mi * 16 + lr * 4 + r;
        const int qg = qt * 128 + qlocal;
        float vv[4];
        float mx = -INFINITY;
#pragma unroll
        for (int nj = 0; nj < 4; ++nj) {
          int kg = t * 64 + nj * 16 + lc;
          float val = s[mi][nj][r] * 0.125f;
          val = (kg <= qg) ? val : -INFINITY;
          vv[nj] = val;
          mx = fmaxf(mx, val);
        }
#pragma unroll
        for (int off = 1; off < 16; off <<= 1) mx = fmaxf(mx, __shfl_xor(mx, off));
        float mold = m_run[mi][r];
        float mnew = fmaxf(mold, mx);
        float sf = __expf(mold - mnew);
        m_run[mi][r] = mnew;
        float ps = 0.f;
#pragma unroll
        for (int nj = 0; nj < 4; ++nj) {
          float p = __expf(vv[nj] - mnew);
          ps += p;
          int key = nj * 16 + lc;
          *(u16*)((char*)Ps + qlocal * 128 + ((key * 2) ^ ((qlocal & 7) << 4))) = f2bf(p);
        }
#pragma unroll
        for (int off = 1; off < 16; off <<= 1) ps += __shfl_xor(ps, off);
        l_run[mi][r] = l_run[mi][r] * sf + ps;
#pragma unroll
        for (int dj = 0; dj < 4; ++dj) o_acc[mi][dj][r] *= sf;
      }
    }

    // O += P V  (A-frags from Ps, B-frags from Vt)
#pragma unroll
    for (int ks = 0; ks < 2; ++ks) {
      s16x8 pf[2], vf[4];
#pragma unroll
      for (int mi = 0; mi < 2; ++mi) {
        int row = w * 32 + mi * 16 + lc;
        int colb = (ks * 64 + lr * 16) ^ ((row & 7) << 4);
        pf[mi] = *(const s16x8*)((const char*)Ps + row * 128 + colb);
      }
#pragma unroll
      for (int dj = 0; dj < 4; ++dj) {
        int row = dj * 16 + lc;
        int colb = (ks * 64 + lr * 16) ^ ((row & 7) << 4);
        vf[dj] = *(const s16x8*)((const char*)Vt + row * 128 + colb);
      }
#pragma unroll
      for (int mi = 0; mi < 2; ++mi)
#pragma unroll
        for (int dj = 0; dj < 4; ++dj)
          o_acc[mi][dj] = __builtin_amdgcn_mfma_f32_16x16x32_bf16(
              pf[mi], vf[dj], o_acc[mi][dj], 0, 0, 0);
    }
  }

  // normalize + write O[b, s, h*64+d] as bf16 (feeds proj GEMM)
#pragma unroll
  for (int mi = 0; mi < 2; ++mi) {
#pragma unroll
    for (int r = 0; r < 4; ++r) {
      float inv = 1.0f / l_run[mi][r];
      int qg = qt * 128 + w * 32 + mi * 16 + lr * 4 + r;
      size_t base = ((size_t)(b * 2048 + qg)) * 1024 + h * 64;
#pragma unroll
      for (int dj = 0; dj < 4; ++dj)
        ob[base + dj * 16 + lc] = __float2bfloat16(o_acc[mi][dj][r] * inv);
    }
  }
}

extern "C" void kernel_launch(void* const* d_in, const int* in_sizes, int n_in,
                              void* d_out, int out_size, void* d_ws, size_t ws_size,
                              hipStream_t stream) {
  const float* x = (const float*)d_in[0];
  const float* Wqkv = (const float*)d_in[1];
  const float* bqkv = (const float*)d_in[2];
  const float* Wproj = (const float*)d_in[3];
  const float* bproj = (const float*)d_in[4];
  float* out = (float*)d_out;

  char* ws = (char*)d_ws;
  bf16* xb = (bf16*)(ws);                  // 8 MB, reused as attention output
  bf16* Wt1 = (bf16*)(ws + 8388608);       // 6 MB: W_qkv^T [3072][1024]
  bf16* Wt2 = (bf16*)(ws + 14680064);      // 2 MB: W_proj^T [1024][1024]
  bf16* qb = (bf16*)(ws + 16777216);       // 8 MB each
  bf16* kb = (bf16*)(ws + 25165824);
  bf16* vb = (bf16*)(ws + 33554432);
  bf16* Ob = xb;

  cast_f32_bf16<<<2048, 256, 0, stream>>>(x, xb, 4096 * 1024);
  transpose_cast<<<dim3(48, 16), 256, 0, stream>>>(Wqkv, Wt1, 1024, 3072);
  transpose_cast<<<dim3(16, 16), 256, 0, stream>>>(Wproj, Wt2, 1024, 1024);
  gemm_bt<0><<<dim3(32, 24), 256, 0, stream>>>(xb, Wt1, bqkv, qb, kb, vb, nullptr,
                                               4096, 3072, 1024);
  attn_kernel<<<512, 256, 0, stream>>>(qb, kb, vb, Ob);
  gemm_bt<1><<<dim3(32, 8), 256, 0, stream>>>(Ob, Wt2, bproj, nullptr, nullptr, nullptr,
                                              out, 4096, 1024, 1024);
}